// Round 16
// baseline (192.401 us; speedup 1.0000x reference)
//
#include <hip/hip_runtime.h>
#include <hip/hip_bf16.h>

#define N_NODES 50000
#define E_EDGES 600000
#define HDIM    128

#define QKV_BLOCKS  ((N_NODES + 63) / 64)     // 782 (64 rows/block, x3 mats grid.y)
#define EDGE_BLOCKS ((E_EDGES + 255) / 256)   // 2344
#define SCAN_BLOCKS ((N_NODES + 255) / 256)   // 196
#define ROW_BLOCKS  (N_NODES / 4)             // 12500 (4 waves/block, 1 wave/row)

typedef float f32x4  __attribute__((ext_vector_type(4)));
typedef short short8 __attribute__((ext_vector_type(8)));

__device__ __forceinline__ unsigned short f2bf(float f) {
    __hip_bfloat16 h = __float2bfloat16(f);
    return *reinterpret_cast<unsigned short*>(&h);
}

// ---- Phase 0: split W into bf16 hi/lo ONCE (was redone by every qkv block) ----
__global__ __launch_bounds__(256) void wconv_kernel(
    const float* __restrict__ Wq, const float* __restrict__ Wk,
    const float* __restrict__ Wv,
    unsigned short* __restrict__ Wh, unsigned short* __restrict__ Wl)
{
    const int i = blockIdx.x * 256 + threadIdx.x;   // 192 blocks x 256 = 49152
    if (i >= 3 * HDIM * HDIM) return;
    const int mat = i / (HDIM * HDIM);
    const int idx = i - mat * (HDIM * HDIM);
    const float* W = (mat == 0) ? Wq : (mat == 1) ? Wk : Wv;
    const float f = W[idx];
    const unsigned u = __float_as_uint(f);
    Wh[i] = (unsigned short)(u >> 16);
    Wl[i] = f2bf(f - __uint_as_float(u & 0xffff0000u));
}

// ---- Phase 1 (MFMA): Y = x W^T + b for W in {Wq,Wk,Wv} (blockIdx.y picks mat)
// Split precision: x = xh + xl, W = Wh + Wl (bf16); Y = xh*Wh + xl*Wh + xh*Wl.
// NOTE: fusing the 3 mats into one block was tried (r12-r14) and always loses
// (VGPR live-range cliff / spills). grid.y=3 is the measured optimum.
__global__ __launch_bounds__(256) void qkv_mfma_kernel(
    const float* __restrict__ x,
    const unsigned short* __restrict__ Wh, const unsigned short* __restrict__ Wl,
    const float* __restrict__ bq, const float* __restrict__ bk,
    const float* __restrict__ bv,
    float* __restrict__ Q, unsigned short* __restrict__ Kb,
    unsigned short* __restrict__ Vb)
{
    __shared__ __align__(16) unsigned short Ah[64 * HDIM];  // 16 KB
    __shared__ __align__(16) unsigned short Al[64 * HDIM];  // 16 KB
    const int r0  = blockIdx.x * 64;
    const int mat = blockIdx.y;          // 0=Q 1=K 2=V

    // ---- stage x rows 64x128 as bf16 hi/lo, swizzled ----
    for (int t = threadIdx.x; t < 2048; t += 256) {
        const int r  = t >> 5;           // 0..63
        const int k4 = t & 31;           // float4 index 0..31
        int gr = r0 + r; if (gr >= N_NODES) gr = N_NODES - 1;
        const float4 xv = *(const float4*)&x[(size_t)gr * HDIM + k4 * 4];
        const unsigned ux = __float_as_uint(xv.x), uy = __float_as_uint(xv.y);
        const unsigned uz = __float_as_uint(xv.z), uw = __float_as_uint(xv.w);
        ushort4 hv, lv;
        hv.x = (unsigned short)(ux >> 16); hv.y = (unsigned short)(uy >> 16);
        hv.z = (unsigned short)(uz >> 16); hv.w = (unsigned short)(uw >> 16);
        lv.x = f2bf(xv.x - __uint_as_float(ux & 0xffff0000u));
        lv.y = f2bf(xv.y - __uint_as_float(uy & 0xffff0000u));
        lv.z = f2bf(xv.z - __uint_as_float(uz & 0xffff0000u));
        lv.w = f2bf(xv.w - __uint_as_float(uw & 0xffff0000u));
        const int byte = (r << 8) + (k4 << 3);
        const int swz  = byte ^ ((r & 7) << 4);
        *(ushort4*)((char*)Ah + swz) = hv;
        *(ushort4*)((char*)Al + swz) = lv;
    }

    const int lane = threadIdx.x & 63;
    const int w    = threadIdx.x >> 6;   // wave 0..3
    const int lrow = lane & 15;
    const int lgrp = lane >> 4;
    const int nb   = w * 32;             // wave's col base within mat

    const unsigned short* Whm = Wh + (size_t)mat * HDIM * HDIM;
    const unsigned short* Wlm = Wl + (size_t)mat * HDIM * HDIM;
    const float* bm = (mat == 0) ? bq : (mat == 1) ? bk : bv;

    // ---- B fragments: pre-split bf16, straight 16B loads ----
    short8 Bh[2][4], Bl[2][4];
#pragma unroll
    for (int st = 0; st < 2; ++st) {
        const int col = nb + st * 16 + lrow;
#pragma unroll
        for (int ks = 0; ks < 4; ++ks) {
            const int k0 = ks * 32 + lgrp * 8;
            Bh[st][ks] = *(const short8*)&Whm[(size_t)col * HDIM + k0];
            Bl[st][ks] = *(const short8*)&Wlm[(size_t)col * HDIM + k0];
        }
    }
    const float bias0 = bm[nb + lrow];
    const float bias1 = bm[nb + 16 + lrow];

    __syncthreads();

    // ---- compute: 4 M-subtiles of 16 rows ----
#pragma unroll
    for (int s = 0; s < 4; ++s) {
        f32x4 acc0 = {0.f, 0.f, 0.f, 0.f};
        f32x4 acc1 = {0.f, 0.f, 0.f, 0.f};
        const int row = s * 16 + lrow;
#pragma unroll
        for (int ks = 0; ks < 4; ++ks) {
            const int byte = (row << 8) + ((ks * 32 + lgrp * 8) << 1);
            const int swz  = byte ^ ((row & 7) << 4);
            const short8 ah = *(const short8*)((const char*)Ah + swz);
            const short8 al = *(const short8*)((const char*)Al + swz);
            acc0 = __builtin_amdgcn_mfma_f32_16x16x32_bf16(ah, Bh[0][ks], acc0, 0, 0, 0);
            acc0 = __builtin_amdgcn_mfma_f32_16x16x32_bf16(al, Bh[0][ks], acc0, 0, 0, 0);
            acc0 = __builtin_amdgcn_mfma_f32_16x16x32_bf16(ah, Bl[0][ks], acc0, 0, 0, 0);
            acc1 = __builtin_amdgcn_mfma_f32_16x16x32_bf16(ah, Bh[1][ks], acc1, 0, 0, 0);
            acc1 = __builtin_amdgcn_mfma_f32_16x16x32_bf16(al, Bh[1][ks], acc1, 0, 0, 0);
            acc1 = __builtin_amdgcn_mfma_f32_16x16x32_bf16(ah, Bl[1][ks], acc1, 0, 0, 0);
        }
        const int orow0 = r0 + s * 16 + lgrp * 4;
        if (mat == 0) {
#pragma unroll
            for (int i = 0; i < 4; ++i) {
                const int row_o = orow0 + i;
                if (row_o < N_NODES) {
                    Q[(size_t)row_o * HDIM + nb + lrow]      = acc0[i] + bias0;
                    Q[(size_t)row_o * HDIM + nb + 16 + lrow] = acc1[i] + bias1;
                }
            }
        } else {
            unsigned short* dst = (mat == 1) ? Kb : Vb;
#pragma unroll
            for (int i = 0; i < 4; ++i) {
                const int row_o = orow0 + i;
                if (row_o < N_NODES) {
                    dst[(size_t)row_o * HDIM + nb + lrow]      = f2bf(acc0[i] + bias0);
                    dst[(size_t)row_o * HDIM + nb + 16 + lrow] = f2bf(acc1[i] + bias1);
                }
            }
        }
    }
}

// ---- Phase 2a: histogram of destination rows ----
__global__ __launch_bounds__(256) void hist_kernel(
    const int* __restrict__ ei, int* __restrict__ counts)
{
    const int e = blockIdx.x * 256 + threadIdx.x;
    if (e < E_EDGES) atomicAdd(&counts[ei[e]], 1);
}

// ---- Phase 2b: exclusive prefix scan (3 small kernels) ----
__global__ __launch_bounds__(256) void scan_partial_kernel(
    const int* __restrict__ counts, int* __restrict__ offs, int* __restrict__ aux)
{
    __shared__ int s[256];
    const int i = blockIdx.x * 256 + threadIdx.x;
    const int v = (i < N_NODES) ? counts[i] : 0;
    s[threadIdx.x] = v;
    __syncthreads();
    for (int d = 1; d < 256; d <<= 1) {
        int t = (threadIdx.x >= d) ? s[threadIdx.x - d] : 0;
        __syncthreads();
        s[threadIdx.x] += t;
        __syncthreads();
    }
    if (i < N_NODES) offs[i] = s[threadIdx.x] - v;   // exclusive within block
    if (threadIdx.x == 255) aux[blockIdx.x] = s[255];
}

__global__ __launch_bounds__(256) void scan_aux_kernel(int* __restrict__ aux)
{
    __shared__ int s[256];
    const int i = threadIdx.x;
    const int v = (i < SCAN_BLOCKS) ? aux[i] : 0;
    s[i] = v;
    __syncthreads();
    for (int d = 1; d < 256; d <<= 1) {
        int t = (i >= d) ? s[i - d] : 0;
        __syncthreads();
        s[i] += t;
        __syncthreads();
    }
    if (i < SCAN_BLOCKS) aux[i] = s[i] - v;          // exclusive
}

__global__ __launch_bounds__(256) void scan_add_kernel(
    int* __restrict__ offs, const int* __restrict__ aux, int* __restrict__ cursor)
{
    const int i = blockIdx.x * 256 + threadIdx.x;
    if (i < N_NODES) {
        const int o = offs[i] + aux[blockIdx.x];
        offs[i] = o;
        cursor[i] = o;
    }
}

// ---- Phase 2c: bin edges by destination row; ONE 8B record per edge ----
__global__ __launch_bounds__(256) void bin_kernel(
    const int* __restrict__ ei, const float* __restrict__ ew,
    int* __restrict__ cursor, uint2* __restrict__ erec)
{
    const int e = blockIdx.x * 256 + threadIdx.x;
    if (e >= E_EDGES) return;
    const int row = ei[e];
    const int pos = atomicAdd(&cursor[row], 1);
    erec[pos] = make_uint2((unsigned)ei[E_EDGES + e], __float_as_uint(ew[e]));
}

// ---- Phase 3: energy + exp fused (no global max needed: |en| <= ~6, exp is
// overflow-safe in fp32; softmax is shift-invariant). Writes p = exp(en) and
// per-block partial sums. 8 edges/wave in flight. ----
__global__ __launch_bounds__(256) void energy_kernel(
    const float* __restrict__ Q, const unsigned short* __restrict__ Kb,
    const int* __restrict__ offs, const int* __restrict__ counts,
    uint2* __restrict__ erec, float* __restrict__ blocksum)
{
    const int row  = (blockIdx.x * 256 + threadIdx.x) >> 6;
    const int lane = threadIdx.x & 63;
    const int eg   = lane >> 4;     // edge group 0..3
    const int sl   = lane & 15;     // sub-lane in group
    const int start = offs[row], len = counts[row];
    const float4 q0 = *(const float4*)&Q[(size_t)row * HDIM + sl * 8];
    const float4 q1 = *(const float4*)&Q[(size_t)row * HDIM + sl * 8 + 4];
    const uint4* kb128 = (const uint4*)Kb;   // one row = 16 uint4
    const float inv_scale = 0.08838834764831845f;  // 1/sqrt(128)
    float psum = 0.f;
    for (int j0 = 0; j0 < len; j0 += 8) {
        const int  jA = j0 + eg,      jB = j0 + 4 + eg;
        const bool vA = jA < len,     vB = jB < len;
        const int  eA = start + (vA ? jA : 0);
        const int  eB = start + (vB ? jB : 0);
        const uint2 rA = erec[eA];
        const uint2 rB = erec[eB];
        const uint4 uA = kb128[(size_t)rA.x * 16 + sl];
        const uint4 uB = kb128[(size_t)rB.x * 16 + sl];
        float dA = q0.x * __uint_as_float(uA.x << 16)
                 + q0.y * __uint_as_float(uA.x & 0xffff0000u)
                 + q0.z * __uint_as_float(uA.y << 16)
                 + q0.w * __uint_as_float(uA.y & 0xffff0000u)
                 + q1.x * __uint_as_float(uA.z << 16)
                 + q1.y * __uint_as_float(uA.z & 0xffff0000u)
                 + q1.z * __uint_as_float(uA.w << 16)
                 + q1.w * __uint_as_float(uA.w & 0xffff0000u);
        float dB = q0.x * __uint_as_float(uB.x << 16)
                 + q0.y * __uint_as_float(uB.x & 0xffff0000u)
                 + q0.z * __uint_as_float(uB.y << 16)
                 + q0.w * __uint_as_float(uB.y & 0xffff0000u)
                 + q1.x * __uint_as_float(uB.z << 16)
                 + q1.y * __uint_as_float(uB.z & 0xffff0000u)
                 + q1.z * __uint_as_float(uB.w << 16)
                 + q1.w * __uint_as_float(uB.w & 0xffff0000u);
#pragma unroll
        for (int m = 8; m >= 1; m >>= 1) {
            dA += __shfl_xor(dA, m);
            dB += __shfl_xor(dB, m);
        }
        const float pA = __expf(dA * inv_scale * __uint_as_float(rA.y));
        const float pB = __expf(dB * inv_scale * __uint_as_float(rB.y));
        if (vA && sl == 0) { ((float*)erec)[2 * eA + 1] = pA; psum += pA; }
        if (vB && sl == 0) { ((float*)erec)[2 * eB + 1] = pB; psum += pB; }
    }
    // psum lives on lanes 0,16,32,48; fold across the 4 groups
    psum += __shfl_xor(psum, 16);
    psum += __shfl_xor(psum, 32);
    __shared__ float sm[4];
    if (lane == 0) sm[threadIdx.x >> 6] = psum;
    __syncthreads();
    if (threadIdx.x == 0)
        blocksum[blockIdx.x] = sm[0] + sm[1] + sm[2] + sm[3];
}

__global__ __launch_bounds__(256) void reduce_sum_kernel(
    const float* __restrict__ bs, int n, float* __restrict__ gsum)
{
    float v = 0.f;
    for (int i = threadIdx.x; i < n; i += 256) v += bs[i];
#pragma unroll
    for (int s = 32; s >= 1; s >>= 1) v += __shfl_xor(v, s);
    __shared__ float sm[4];
    if ((threadIdx.x & 63) == 0) sm[threadIdx.x >> 6] = v;
    __syncthreads();
    if (threadIdx.x == 0) *gsum = sm[0] + sm[1] + sm[2] + sm[3];
}

// ---- Phase 5: out[row] = sum_j V[col_j] * p_j / gsum; 8 edges in flight ----
__global__ __launch_bounds__(256) void accum_kernel(
    const unsigned short* __restrict__ Vb,
    const int* __restrict__ offs, const int* __restrict__ counts,
    const uint2* __restrict__ erec, const float* __restrict__ gsum,
    float* __restrict__ out)
{
    const int row  = (blockIdx.x * 256 + threadIdx.x) >> 6;
    const int lane = threadIdx.x & 63;
    const int eg   = lane >> 4;     // edge group 0..3
    const int sl   = lane & 15;     // sub-lane: dims sl*8..sl*8+7
    const float inv = 1.0f / *gsum;
    const int start = offs[row], len = counts[row];
    const uint4* vb128 = (const uint4*)Vb;   // one row = 16 uint4
    float aA[8] = {0.f, 0.f, 0.f, 0.f, 0.f, 0.f, 0.f, 0.f};
    float aB[8] = {0.f, 0.f, 0.f, 0.f, 0.f, 0.f, 0.f, 0.f};
    for (int j0 = 0; j0 < len; j0 += 8) {
        const int  jA = j0 + eg,      jB = j0 + 4 + eg;
        const bool vA = jA < len,     vB = jB < len;
        const int  eA = start + (vA ? jA : 0);
        const int  eB = start + (vB ? jB : 0);
        const uint2 rA = erec[eA];
        const uint2 rB = erec[eB];
        const float wA = vA ? __uint_as_float(rA.y) * inv : 0.f;
        const float wB = vB ? __uint_as_float(rB.y) * inv : 0.f;
        const uint4 uA = vb128[(size_t)rA.x * 16 + sl];
        const uint4 uB = vb128[(size_t)rB.x * 16 + sl];
        aA[0] += __uint_as_float(uA.x << 16) * wA;
        aA[1] += __uint_as_float(uA.x & 0xffff0000u) * wA;
        aA[2] += __uint_as_float(uA.y << 16) * wA;
        aA[3] += __uint_as_float(uA.y & 0xffff0000u) * wA;
        aA[4] += __uint_as_float(uA.z << 16) * wA;
        aA[5] += __uint_as_float(uA.z & 0xffff0000u) * wA;
        aA[6] += __uint_as_float(uA.w << 16) * wA;
        aA[7] += __uint_as_float(uA.w & 0xffff0000u) * wA;
        aB[0] += __uint_as_float(uB.x << 16) * wB;
        aB[1] += __uint_as_float(uB.x & 0xffff0000u) * wB;
        aB[2] += __uint_as_float(uB.y << 16) * wB;
        aB[3] += __uint_as_float(uB.y & 0xffff0000u) * wB;
        aB[4] += __uint_as_float(uB.z << 16) * wB;
        aB[5] += __uint_as_float(uB.z & 0xffff0000u) * wB;
        aB[6] += __uint_as_float(uB.w << 16) * wB;
        aB[7] += __uint_as_float(uB.w & 0xffff0000u) * wB;
    }
    float a[8];
#pragma unroll
    for (int i = 0; i < 8; ++i) {
        a[i] = aA[i] + aB[i];
        a[i] += __shfl_xor(a[i], 16);
        a[i] += __shfl_xor(a[i], 32);
    }
    if (eg == 0) {
        float* o = out + (size_t)row * HDIM + sl * 8;
        *(float4*)o       = make_float4(a[0], a[1], a[2], a[3]);
        *(float4*)(o + 4) = make_float4(a[4], a[5], a[6], a[7]);
    }
}

extern "C" void kernel_launch(void* const* d_in, const int* in_sizes, int n_in,
                              void* d_out, int out_size, void* d_ws, size_t ws_size,
                              hipStream_t stream)
{
    const float* x  = (const float*)d_in[0];
    const int*   ei = (const int*)d_in[1];
    const float* ew = (const float*)d_in[2];
    const float* Wq = (const float*)d_in[3];
    const float* bq = (const float*)d_in[4];
    const float* Wk = (const float*)d_in[5];
    const float* bk = (const float*)d_in[6];
    const float* Wv = (const float*)d_in[7];
    const float* bv = (const float*)d_in[8];
    float* out = (float*)d_out;

    float* ws = (float*)d_ws;
    float* Q       = ws;                                  // N*H fp32
    unsigned short* Kb = (unsigned short*)(Q + (size_t)N_NODES * HDIM);  // N*H bf16
    unsigned short* Vb = Kb + (size_t)N_NODES * HDIM;     // N*H bf16
    unsigned short* Wh = Vb + (size_t)N_NODES * HDIM;     // 3*H*H bf16
    unsigned short* Wl = Wh + 3 * HDIM * HDIM;            // 3*H*H bf16
    int*   counts  = (int*)(Wl + 3 * HDIM * HDIM);        // N
    int*   offs    = counts + N_NODES;                    // N
    int*   cursor  = offs + N_NODES;                      // N
    int*   aux     = cursor + N_NODES;                    // SCAN_BLOCKS (256 slots)
    uint2* erec    = (uint2*)(aux + 256);                 // E records (col, ew/p)
    float* blocksum= (float*)(erec + E_EDGES);            // ROW_BLOCKS
    float* gsum    = blocksum + ROW_BLOCKS;               // 1

    hipMemsetAsync(counts, 0, N_NODES * sizeof(int), stream);

    wconv_kernel<<<192, 256, 0, stream>>>(Wq, Wk, Wv, Wh, Wl);
    qkv_mfma_kernel<<<dim3(QKV_BLOCKS, 3), 256, 0, stream>>>(
        x, Wh, Wl, bq, bk, bv, Q, Kb, Vb);
    hist_kernel<<<EDGE_BLOCKS, 256, 0, stream>>>(ei, counts);
    scan_partial_kernel<<<SCAN_BLOCKS, 256, 0, stream>>>(counts, offs, aux);
    scan_aux_kernel<<<1, 256, 0, stream>>>(aux);
    scan_add_kernel<<<SCAN_BLOCKS, 256, 0, stream>>>(offs, aux, cursor);
    bin_kernel<<<EDGE_BLOCKS, 256, 0, stream>>>(ei, ew, cursor, erec);
    energy_kernel<<<ROW_BLOCKS, 256, 0, stream>>>(Q, Kb, offs, counts, erec, blocksum);
    reduce_sum_kernel<<<1, 256, 0, stream>>>(blocksum, ROW_BLOCKS, gsum);
    accum_kernel<<<ROW_BLOCKS, 256, 0, stream>>>(Vb, offs, counts, erec, gsum, out);
}

// Round 17
// 185.993 us; speedup vs baseline: 1.0345x; 1.0345x over previous
//
#include <hip/hip_runtime.h>
#include <hip/hip_bf16.h>

#define N_NODES 50000
#define E_EDGES 600000
#define HDIM    128

#define QKV_BLOCKS  ((N_NODES + 63) / 64)     // 782 (64 rows/block) x3 mats
#define EDGE_BLOCKS ((E_EDGES + 255) / 256)   // 2344
#define SCAN_BLOCKS ((N_NODES + 255) / 256)   // 196
#define ROW_BLOCKS  (N_NODES / 4)             // 12500 (4 waves/block, 1 wave/row)

typedef float f32x4  __attribute__((ext_vector_type(4)));
typedef short short8 __attribute__((ext_vector_type(8)));

__device__ __forceinline__ unsigned short f2bf(float f) {
    __hip_bfloat16 h = __float2bfloat16(f);
    return *reinterpret_cast<unsigned short*>(&h);
}
__device__ __forceinline__ float bflo(unsigned u) { return __uint_as_float(u << 16); }
__device__ __forceinline__ float bfhi(unsigned u) { return __uint_as_float(u & 0xffff0000u); }

// ---- Phase 1 (MFMA) + hist fused in one launch.
// Blocks [0, 3*QKV_BLOCKS): Y = x W^T + b (blockgroup picks mat; split-precision
//   bf16 hi/lo MFMA: Y = xh*Wh + xl*Wh + xh*Bl). In-kernel W split (wconv
//   pre-pass REGRESSED qkv 42->46, r16). Mat fusion REGRESSED (r12-r14: VGPR
//   cliff/spills) -- one mat per block is the measured optimum.
// Blocks [3*QKV_BLOCKS, +EDGE_BLOCKS): histogram of destination rows
//   (independent work, fills qkv's latency bubbles; saves a launch).
__global__ __launch_bounds__(256) void qkv_hist_kernel(
    const float* __restrict__ x,
    const float* __restrict__ Wq, const float* __restrict__ bq,
    const float* __restrict__ Wk, const float* __restrict__ bk,
    const float* __restrict__ Wv, const float* __restrict__ bv,
    const int* __restrict__ ei, int* __restrict__ counts,
    float* __restrict__ Q, unsigned short* __restrict__ Kb,
    unsigned short* __restrict__ Vb)
{
    __shared__ __align__(16) unsigned short Ah[64 * HDIM];  // 16 KB
    __shared__ __align__(16) unsigned short Al[64 * HDIM];  // 16 KB
    const int bid = blockIdx.x;
    if (bid >= 3 * QKV_BLOCKS) {   // ---- hist path ----
        const int e = (bid - 3 * QKV_BLOCKS) * 256 + threadIdx.x;
        if (e < E_EDGES) atomicAdd(&counts[ei[e]], 1);
        return;
    }
    const int mat = bid / QKV_BLOCKS;        // 0=Q 1=K 2=V
    const int r0  = (bid - mat * QKV_BLOCKS) * 64;

    // ---- stage x rows 64x128 as bf16 hi/lo, swizzled ----
    for (int t = threadIdx.x; t < 2048; t += 256) {
        const int r  = t >> 5;           // 0..63
        const int k4 = t & 31;           // float4 index 0..31
        int gr = r0 + r; if (gr >= N_NODES) gr = N_NODES - 1;
        const float4 xv = *(const float4*)&x[(size_t)gr * HDIM + k4 * 4];
        const unsigned ux = __float_as_uint(xv.x), uy = __float_as_uint(xv.y);
        const unsigned uz = __float_as_uint(xv.z), uw = __float_as_uint(xv.w);
        ushort4 hv, lv;
        hv.x = (unsigned short)(ux >> 16); hv.y = (unsigned short)(uy >> 16);
        hv.z = (unsigned short)(uz >> 16); hv.w = (unsigned short)(uw >> 16);
        lv.x = f2bf(xv.x - __uint_as_float(ux & 0xffff0000u));
        lv.y = f2bf(xv.y - __uint_as_float(uy & 0xffff0000u));
        lv.z = f2bf(xv.z - __uint_as_float(uz & 0xffff0000u));
        lv.w = f2bf(xv.w - __uint_as_float(uw & 0xffff0000u));
        const int byte = (r << 8) + (k4 << 3);
        const int swz  = byte ^ ((r & 7) << 4);
        *(ushort4*)((char*)Ah + swz) = hv;
        *(ushort4*)((char*)Al + swz) = lv;
    }

    const int lane = threadIdx.x & 63;
    const int w    = threadIdx.x >> 6;   // wave 0..3
    const int lrow = lane & 15;
    const int lgrp = lane >> 4;
    const int nb   = w * 32;             // wave's col base within mat

    const float* Wm = (mat == 0) ? Wq : (mat == 1) ? Wk : Wv;
    const float* bm = (mat == 0) ? bq : (mat == 1) ? bk : bv;

    // ---- B fragments: hi/lo split in-register, 2 strips x 4 k-steps ----
    short8 Bh[2][4], Bl[2][4];
#pragma unroll
    for (int st = 0; st < 2; ++st) {
        const int col = nb + st * 16 + lrow;
#pragma unroll
        for (int ks = 0; ks < 4; ++ks) {
            const int k0 = ks * 32 + lgrp * 8;
            const float* p = Wm + (size_t)col * HDIM + k0;
            const float4 a = *(const float4*)p;
            const float4 b = *(const float4*)(p + 4);
            const float f[8] = {a.x, a.y, a.z, a.w, b.x, b.y, b.z, b.w};
            short8 h, l;
#pragma unroll
            for (int j = 0; j < 8; ++j) {
                const unsigned u = __float_as_uint(f[j]);
                h[j] = (short)(u >> 16);
                l[j] = (short)f2bf(f[j] - __uint_as_float(u & 0xffff0000u));
            }
            Bh[st][ks] = h; Bl[st][ks] = l;
        }
    }
    const float bias0 = bm[nb + lrow];
    const float bias1 = bm[nb + 16 + lrow];

    __syncthreads();

    // ---- compute: 4 M-subtiles of 16 rows ----
#pragma unroll
    for (int s = 0; s < 4; ++s) {
        f32x4 acc0 = {0.f, 0.f, 0.f, 0.f};
        f32x4 acc1 = {0.f, 0.f, 0.f, 0.f};
        const int row = s * 16 + lrow;
#pragma unroll
        for (int ks = 0; ks < 4; ++ks) {
            const int byte = (row << 8) + ((ks * 32 + lgrp * 8) << 1);
            const int swz  = byte ^ ((row & 7) << 4);
            const short8 ah = *(const short8*)((const char*)Ah + swz);
            const short8 al = *(const short8*)((const char*)Al + swz);
            acc0 = __builtin_amdgcn_mfma_f32_16x16x32_bf16(ah, Bh[0][ks], acc0, 0, 0, 0);
            acc0 = __builtin_amdgcn_mfma_f32_16x16x32_bf16(al, Bh[0][ks], acc0, 0, 0, 0);
            acc0 = __builtin_amdgcn_mfma_f32_16x16x32_bf16(ah, Bl[0][ks], acc0, 0, 0, 0);
            acc1 = __builtin_amdgcn_mfma_f32_16x16x32_bf16(ah, Bh[1][ks], acc1, 0, 0, 0);
            acc1 = __builtin_amdgcn_mfma_f32_16x16x32_bf16(al, Bh[1][ks], acc1, 0, 0, 0);
            acc1 = __builtin_amdgcn_mfma_f32_16x16x32_bf16(ah, Bl[1][ks], acc1, 0, 0, 0);
        }
        const int orow0 = r0 + s * 16 + lgrp * 4;
        if (mat == 0) {
#pragma unroll
            for (int i = 0; i < 4; ++i) {
                const int row_o = orow0 + i;
                if (row_o < N_NODES) {
                    Q[(size_t)row_o * HDIM + nb + lrow]      = acc0[i] + bias0;
                    Q[(size_t)row_o * HDIM + nb + 16 + lrow] = acc1[i] + bias1;
                }
            }
        } else {
            unsigned short* dst = (mat == 1) ? Kb : Vb;
#pragma unroll
            for (int i = 0; i < 4; ++i) {
                const int row_o = orow0 + i;
                if (row_o < N_NODES) {
                    dst[(size_t)row_o * HDIM + nb + lrow]      = f2bf(acc0[i] + bias0);
                    dst[(size_t)row_o * HDIM + nb + 16 + lrow] = f2bf(acc1[i] + bias1);
                }
            }
        }
    }
}

// ---- Phase 2b: exclusive prefix scan (3 small kernels) ----
__global__ __launch_bounds__(256) void scan_partial_kernel(
    const int* __restrict__ counts, int* __restrict__ offs, int* __restrict__ aux)
{
    __shared__ int s[256];
    const int i = blockIdx.x * 256 + threadIdx.x;
    const int v = (i < N_NODES) ? counts[i] : 0;
    s[threadIdx.x] = v;
    __syncthreads();
    for (int d = 1; d < 256; d <<= 1) {
        int t = (threadIdx.x >= d) ? s[threadIdx.x - d] : 0;
        __syncthreads();
        s[threadIdx.x] += t;
        __syncthreads();
    }
    if (i < N_NODES) offs[i] = s[threadIdx.x] - v;   // exclusive within block
    if (threadIdx.x == 255) aux[blockIdx.x] = s[255];
}

__global__ __launch_bounds__(256) void scan_aux_kernel(int* __restrict__ aux)
{
    __shared__ int s[256];
    const int i = threadIdx.x;
    const int v = (i < SCAN_BLOCKS) ? aux[i] : 0;
    s[i] = v;
    __syncthreads();
    for (int d = 1; d < 256; d <<= 1) {
        int t = (i >= d) ? s[i - d] : 0;
        __syncthreads();
        s[i] += t;
        __syncthreads();
    }
    if (i < SCAN_BLOCKS) aux[i] = s[i] - v;          // exclusive
}

__global__ __launch_bounds__(256) void scan_add_kernel(
    int* __restrict__ offs, const int* __restrict__ aux, int* __restrict__ cursor)
{
    const int i = blockIdx.x * 256 + threadIdx.x;
    if (i < N_NODES) {
        const int o = offs[i] + aux[blockIdx.x];
        offs[i] = o;
        cursor[i] = o;
    }
}

// ---- Phase 2c: bin edges by destination row; ONE 8B record per edge ----
__global__ __launch_bounds__(256) void bin_kernel(
    const int* __restrict__ ei, const float* __restrict__ ew,
    int* __restrict__ cursor, uint2* __restrict__ erec)
{
    const int e = blockIdx.x * 256 + threadIdx.x;
    if (e >= E_EDGES) return;
    const int row = ei[e];
    const int pos = atomicAdd(&cursor[row], 1);
    erec[pos] = make_uint2((unsigned)ei[E_EDGES + e], __float_as_uint(ew[e]));
}

// ---- Phase 3: energy + exp fused (no global max: |en| <= ~6, overflow-safe;
// softmax is shift-invariant). 16 edges/wave in flight (4 groups x4 unroll).
__global__ __launch_bounds__(256) void energy_kernel(
    const float* __restrict__ Q, const unsigned short* __restrict__ Kb,
    const int* __restrict__ offs, const int* __restrict__ counts,
    uint2* __restrict__ erec, float* __restrict__ blocksum)
{
    const int row  = (blockIdx.x * 256 + threadIdx.x) >> 6;
    const int lane = threadIdx.x & 63;
    const int eg   = lane >> 4;     // edge group 0..3
    const int sl   = lane & 15;     // sub-lane in group
    const int start = offs[row], len = counts[row];
    const float4 q0 = *(const float4*)&Q[(size_t)row * HDIM + sl * 8];
    const float4 q1 = *(const float4*)&Q[(size_t)row * HDIM + sl * 8 + 4];
    const uint4* kb128 = (const uint4*)Kb;   // one row = 16 uint4
    const float inv_scale = 0.08838834764831845f;  // 1/sqrt(128)
    float psum = 0.f;
    for (int j0 = 0; j0 < len; j0 += 16) {
        int   e[4]; bool v[4]; uint2 r[4]; uint4 u[4];
#pragma unroll
        for (int c = 0; c < 4; ++c) {
            const int jj = j0 + c * 4 + eg;
            v[c] = jj < len;
            e[c] = start + (v[c] ? jj : 0);
            r[c] = erec[e[c]];
        }
#pragma unroll
        for (int c = 0; c < 4; ++c)
            u[c] = kb128[(size_t)r[c].x * 16 + sl];
#pragma unroll
        for (int c = 0; c < 4; ++c) {
            float d = q0.x * bflo(u[c].x) + q0.y * bfhi(u[c].x)
                    + q0.z * bflo(u[c].y) + q0.w * bfhi(u[c].y)
                    + q1.x * bflo(u[c].z) + q1.y * bfhi(u[c].z)
                    + q1.z * bflo(u[c].w) + q1.w * bfhi(u[c].w);
#pragma unroll
            for (int m = 8; m >= 1; m >>= 1) d += __shfl_xor(d, m);
            const float p = __expf(d * inv_scale * __uint_as_float(r[c].y));
            if (v[c] && sl == 0) { ((float*)erec)[2 * e[c] + 1] = p; psum += p; }
        }
    }
    // psum lives on lanes 0,16,32,48; fold across the 4 groups
    psum += __shfl_xor(psum, 16);
    psum += __shfl_xor(psum, 32);
    __shared__ float sm[4];
    if (lane == 0) sm[threadIdx.x >> 6] = psum;
    __syncthreads();
    if (threadIdx.x == 0)
        blocksum[blockIdx.x] = sm[0] + sm[1] + sm[2] + sm[3];
}

__global__ __launch_bounds__(256) void reduce_sum_kernel(
    const float* __restrict__ bs, int n, float* __restrict__ gsum)
{
    float v = 0.f;
    for (int i = threadIdx.x; i < n; i += 256) v += bs[i];
#pragma unroll
    for (int s = 32; s >= 1; s >>= 1) v += __shfl_xor(v, s);
    __shared__ float sm[4];
    if ((threadIdx.x & 63) == 0) sm[threadIdx.x >> 6] = v;
    __syncthreads();
    if (threadIdx.x == 0) *gsum = sm[0] + sm[1] + sm[2] + sm[3];
}

// ---- Phase 5: out[row] = sum_j V[col_j] * p_j / gsum; 16 edges in flight ----
__global__ __launch_bounds__(256) void accum_kernel(
    const unsigned short* __restrict__ Vb,
    const int* __restrict__ offs, const int* __restrict__ counts,
    const uint2* __restrict__ erec, const float* __restrict__ gsum,
    float* __restrict__ out)
{
    const int row  = (blockIdx.x * 256 + threadIdx.x) >> 6;
    const int lane = threadIdx.x & 63;
    const int eg   = lane >> 4;     // edge group 0..3
    const int sl   = lane & 15;     // sub-lane: dims sl*8..sl*8+7
    const float inv = 1.0f / *gsum;
    const int start = offs[row], len = counts[row];
    const uint4* vb128 = (const uint4*)Vb;   // one row = 16 uint4
    float acc[4][8];
#pragma unroll
    for (int c = 0; c < 4; ++c)
#pragma unroll
        for (int k = 0; k < 8; ++k) acc[c][k] = 0.f;
    for (int j0 = 0; j0 < len; j0 += 16) {
        uint2 r[4]; float w[4]; uint4 u[4];
#pragma unroll
        for (int c = 0; c < 4; ++c) {
            const int jj = j0 + c * 4 + eg;
            const bool v = jj < len;
            const int  e = start + (v ? jj : 0);
            r[c] = erec[e];
            w[c] = v ? __uint_as_float(r[c].y) * inv : 0.f;
        }
#pragma unroll
        for (int c = 0; c < 4; ++c)
            u[c] = vb128[(size_t)r[c].x * 16 + sl];
#pragma unroll
        for (int c = 0; c < 4; ++c) {
            acc[c][0] += bflo(u[c].x) * w[c];
            acc[c][1] += bfhi(u[c].x) * w[c];
            acc[c][2] += bflo(u[c].y) * w[c];
            acc[c][3] += bfhi(u[c].y) * w[c];
            acc[c][4] += bflo(u[c].z) * w[c];
            acc[c][5] += bfhi(u[c].z) * w[c];
            acc[c][6] += bflo(u[c].w) * w[c];
            acc[c][7] += bfhi(u[c].w) * w[c];
        }
    }
    float a[8];
#pragma unroll
    for (int k = 0; k < 8; ++k) {
        a[k] = (acc[0][k] + acc[1][k]) + (acc[2][k] + acc[3][k]);
        a[k] += __shfl_xor(a[k], 16);
        a[k] += __shfl_xor(a[k], 32);
    }
    if (eg == 0) {
        float* o = out + (size_t)row * HDIM + sl * 8;
        *(float4*)o       = make_float4(a[0], a[1], a[2], a[3]);
        *(float4*)(o + 4) = make_float4(a[4], a[5], a[6], a[7]);
    }
}

extern "C" void kernel_launch(void* const* d_in, const int* in_sizes, int n_in,
                              void* d_out, int out_size, void* d_ws, size_t ws_size,
                              hipStream_t stream)
{
    const float* x  = (const float*)d_in[0];
    const int*   ei = (const int*)d_in[1];
    const float* ew = (const float*)d_in[2];
    const float* Wq = (const float*)d_in[3];
    const float* bq = (const float*)d_in[4];
    const float* Wk = (const float*)d_in[5];
    const float* bk = (const float*)d_in[6];
    const float* Wv = (const float*)d_in[7];
    const float* bv = (const float*)d_in[8];
    float* out = (float*)d_out;

    float* ws = (float*)d_ws;
    float* Q       = ws;                                  // N*H fp32
    unsigned short* Kb = (unsigned short*)(Q + (size_t)N_NODES * HDIM);  // N*H bf16
    unsigned short* Vb = Kb + (size_t)N_NODES * HDIM;     // N*H bf16
    int*   counts  = (int*)(Vb + (size_t)N_NODES * HDIM); // N
    int*   offs    = counts + N_NODES;                    // N
    int*   cursor  = offs + N_NODES;                      // N
    int*   aux     = cursor + N_NODES;                    // SCAN_BLOCKS (256 slots)
    uint2* erec    = (uint2*)(aux + 256);                 // E records (col, ew/p)
    float* blocksum= (float*)(erec + E_EDGES);            // ROW_BLOCKS
    float* gsum    = blocksum + ROW_BLOCKS;               // 1

    hipMemsetAsync(counts, 0, N_NODES * sizeof(int), stream);

    qkv_hist_kernel<<<3 * QKV_BLOCKS + EDGE_BLOCKS, 256, 0, stream>>>(
        x, Wq, bq, Wk, bk, Wv, bv, ei, counts, Q, Kb, Vb);
    scan_partial_kernel<<<SCAN_BLOCKS, 256, 0, stream>>>(counts, offs, aux);
    scan_aux_kernel<<<1, 256, 0, stream>>>(aux);
    scan_add_kernel<<<SCAN_BLOCKS, 256, 0, stream>>>(offs, aux, cursor);
    bin_kernel<<<EDGE_BLOCKS, 256, 0, stream>>>(ei, ew, cursor, erec);
    energy_kernel<<<ROW_BLOCKS, 256, 0, stream>>>(Q, Kb, offs, counts, erec, blocksum);
    reduce_sum_kernel<<<1, 256, 0, stream>>>(blocksum, ROW_BLOCKS, gsum);
    accum_kernel<<<ROW_BLOCKS, 256, 0, stream>>>(Vb, offs, counts, erec, gsum, out);
}

// Round 18
// 166.481 us; speedup vs baseline: 1.1557x; 1.1172x over previous
//
#include <hip/hip_runtime.h>
#include <hip/hip_bf16.h>

#define N_NODES 50000
#define E_EDGES 600000
#define HDIM    128

#define QKV_BLOCKS  ((N_NODES + 63) / 64)     // 782 (64 rows/block) x3 mats
#define EDGE_BLOCKS ((E_EDGES + 255) / 256)   // 2344
#define SCAN_BLOCKS ((N_NODES + 255) / 256)   // 196
#define ROW_BLOCKS  (N_NODES / 4)             // 12500 (4 waves/block, 1 wave/row)

typedef float f32x4  __attribute__((ext_vector_type(4)));
typedef short short8 __attribute__((ext_vector_type(8)));

__device__ __forceinline__ unsigned short f2bf(float f) {
    __hip_bfloat16 h = __float2bfloat16(f);
    return *reinterpret_cast<unsigned short*>(&h);
}
__device__ __forceinline__ float bflo(unsigned u) { return __uint_as_float(u << 16); }
__device__ __forceinline__ float bfhi(unsigned u) { return __uint_as_float(u & 0xffff0000u); }

// ---- Phase 1 (MFMA): Y = x W^T + b, one mat per block (grid 3*QKV_BLOCKS).
// Each block ALSO histograms 256 edges (inline, overlaps MFMA; no tail blocks).
// Split precision: x = xh + xl, W = Wh + Wl (bf16); Y = xh*Wh + xl*Wh + xh*Wl.
// Mat fusion REGRESSED (r12-r14 VGPR cliff); wconv pre-pass REGRESSED (r16).
__global__ __launch_bounds__(256) void qkv_hist_kernel(
    const float* __restrict__ x,
    const float* __restrict__ Wq, const float* __restrict__ bq,
    const float* __restrict__ Wk, const float* __restrict__ bk,
    const float* __restrict__ Wv, const float* __restrict__ bv,
    const int* __restrict__ ei, int* __restrict__ counts,
    float* __restrict__ Q, unsigned short* __restrict__ Kb,
    unsigned short* __restrict__ Vb)
{
    __shared__ __align__(16) unsigned short Ah[64 * HDIM];  // 16 KB
    __shared__ __align__(16) unsigned short Al[64 * HDIM];  // 16 KB
    const int bid = blockIdx.x;
    const int mat = bid / QKV_BLOCKS;        // 0=Q 1=K 2=V
    const int r0  = (bid - mat * QKV_BLOCKS) * 64;

    // ---- stage x rows 64x128 as bf16 hi/lo, swizzled ----
    for (int t = threadIdx.x; t < 2048; t += 256) {
        const int r  = t >> 5;           // 0..63
        const int k4 = t & 31;           // float4 index 0..31
        int gr = r0 + r; if (gr >= N_NODES) gr = N_NODES - 1;
        const float4 xv = *(const float4*)&x[(size_t)gr * HDIM + k4 * 4];
        const unsigned ux = __float_as_uint(xv.x), uy = __float_as_uint(xv.y);
        const unsigned uz = __float_as_uint(xv.z), uw = __float_as_uint(xv.w);
        ushort4 hv, lv;
        hv.x = (unsigned short)(ux >> 16); hv.y = (unsigned short)(uy >> 16);
        hv.z = (unsigned short)(uz >> 16); hv.w = (unsigned short)(uw >> 16);
        lv.x = f2bf(xv.x - __uint_as_float(ux & 0xffff0000u));
        lv.y = f2bf(xv.y - __uint_as_float(uy & 0xffff0000u));
        lv.z = f2bf(xv.z - __uint_as_float(uz & 0xffff0000u));
        lv.w = f2bf(xv.w - __uint_as_float(uw & 0xffff0000u));
        const int byte = (r << 8) + (k4 << 3);
        const int swz  = byte ^ ((r & 7) << 4);
        *(ushort4*)((char*)Ah + swz) = hv;
        *(ushort4*)((char*)Al + swz) = lv;
    }

    // ---- inline hist: this block's 256-edge chunk (overlaps MFMA phase) ----
    {
        const int e = bid * 256 + threadIdx.x;
        if (e < E_EDGES) atomicAdd(&counts[ei[e]], 1);
    }

    const int lane = threadIdx.x & 63;
    const int w    = threadIdx.x >> 6;   // wave 0..3
    const int lrow = lane & 15;
    const int lgrp = lane >> 4;
    const int nb   = w * 32;             // wave's col base within mat

    const float* Wm = (mat == 0) ? Wq : (mat == 1) ? Wk : Wv;
    const float* bm = (mat == 0) ? bq : (mat == 1) ? bk : bv;

    // ---- B fragments: hi/lo split in-register, 2 strips x 4 k-steps ----
    short8 Bh[2][4], Bl[2][4];
#pragma unroll
    for (int st = 0; st < 2; ++st) {
        const int col = nb + st * 16 + lrow;
#pragma unroll
        for (int ks = 0; ks < 4; ++ks) {
            const int k0 = ks * 32 + lgrp * 8;
            const float* p = Wm + (size_t)col * HDIM + k0;
            const float4 a = *(const float4*)p;
            const float4 b = *(const float4*)(p + 4);
            const float f[8] = {a.x, a.y, a.z, a.w, b.x, b.y, b.z, b.w};
            short8 h, l;
#pragma unroll
            for (int j = 0; j < 8; ++j) {
                const unsigned u = __float_as_uint(f[j]);
                h[j] = (short)(u >> 16);
                l[j] = (short)f2bf(f[j] - __uint_as_float(u & 0xffff0000u));
            }
            Bh[st][ks] = h; Bl[st][ks] = l;
        }
    }
    const float bias0 = bm[nb + lrow];
    const float bias1 = bm[nb + 16 + lrow];

    __syncthreads();

    // ---- compute: 4 M-subtiles of 16 rows ----
#pragma unroll
    for (int s = 0; s < 4; ++s) {
        f32x4 acc0 = {0.f, 0.f, 0.f, 0.f};
        f32x4 acc1 = {0.f, 0.f, 0.f, 0.f};
        const int row = s * 16 + lrow;
#pragma unroll
        for (int ks = 0; ks < 4; ++ks) {
            const int byte = (row << 8) + ((ks * 32 + lgrp * 8) << 1);
            const int swz  = byte ^ ((row & 7) << 4);
            const short8 ah = *(const short8*)((const char*)Ah + swz);
            const short8 al = *(const short8*)((const char*)Al + swz);
            acc0 = __builtin_amdgcn_mfma_f32_16x16x32_bf16(ah, Bh[0][ks], acc0, 0, 0, 0);
            acc0 = __builtin_amdgcn_mfma_f32_16x16x32_bf16(al, Bh[0][ks], acc0, 0, 0, 0);
            acc0 = __builtin_amdgcn_mfma_f32_16x16x32_bf16(ah, Bl[0][ks], acc0, 0, 0, 0);
            acc1 = __builtin_amdgcn_mfma_f32_16x16x32_bf16(ah, Bh[1][ks], acc1, 0, 0, 0);
            acc1 = __builtin_amdgcn_mfma_f32_16x16x32_bf16(al, Bh[1][ks], acc1, 0, 0, 0);
            acc1 = __builtin_amdgcn_mfma_f32_16x16x32_bf16(ah, Bl[1][ks], acc1, 0, 0, 0);
        }
        const int orow0 = r0 + s * 16 + lgrp * 4;
        if (mat == 0) {
#pragma unroll
            for (int i = 0; i < 4; ++i) {
                const int row_o = orow0 + i;
                if (row_o < N_NODES) {
                    Q[(size_t)row_o * HDIM + nb + lrow]      = acc0[i] + bias0;
                    Q[(size_t)row_o * HDIM + nb + 16 + lrow] = acc1[i] + bias1;
                }
            }
        } else {
            unsigned short* dst = (mat == 1) ? Kb : Vb;
#pragma unroll
            for (int i = 0; i < 4; ++i) {
                const int row_o = orow0 + i;
                if (row_o < N_NODES) {
                    dst[(size_t)row_o * HDIM + nb + lrow]      = f2bf(acc0[i] + bias0);
                    dst[(size_t)row_o * HDIM + nb + 16 + lrow] = f2bf(acc1[i] + bias1);
                }
            }
        }
    }
}

// ---- Phase 2b: exclusive prefix scan (3 small kernels) ----
__global__ __launch_bounds__(256) void scan_partial_kernel(
    const int* __restrict__ counts, int* __restrict__ offs, int* __restrict__ aux)
{
    __shared__ int s[256];
    const int i = blockIdx.x * 256 + threadIdx.x;
    const int v = (i < N_NODES) ? counts[i] : 0;
    s[threadIdx.x] = v;
    __syncthreads();
    for (int d = 1; d < 256; d <<= 1) {
        int t = (threadIdx.x >= d) ? s[threadIdx.x - d] : 0;
        __syncthreads();
        s[threadIdx.x] += t;
        __syncthreads();
    }
    if (i < N_NODES) offs[i] = s[threadIdx.x] - v;   // exclusive within block
    if (threadIdx.x == 255) aux[blockIdx.x] = s[255];
}

__global__ __launch_bounds__(256) void scan_aux_kernel(int* __restrict__ aux)
{
    __shared__ int s[256];
    const int i = threadIdx.x;
    const int v = (i < SCAN_BLOCKS) ? aux[i] : 0;
    s[i] = v;
    __syncthreads();
    for (int d = 1; d < 256; d <<= 1) {
        int t = (i >= d) ? s[i - d] : 0;
        __syncthreads();
        s[i] += t;
        __syncthreads();
    }
    if (i < SCAN_BLOCKS) aux[i] = s[i] - v;          // exclusive
}

__global__ __launch_bounds__(256) void scan_add_kernel(
    int* __restrict__ offs, const int* __restrict__ aux, int* __restrict__ cursor)
{
    const int i = blockIdx.x * 256 + threadIdx.x;
    if (i < N_NODES) {
        const int o = offs[i] + aux[blockIdx.x];
        offs[i] = o;
        cursor[i] = o;
    }
}

// ---- Phase 2c: bin edges; ONE PACKED 4B record per edge (col:17 | ew_q15:15).
// 4B scatter halves random-line write-allocate traffic vs the 8B record (r11's
// proven mechanism). ew quantization error <= 1.5e-5 (negligible vs bf16-K).
__global__ __launch_bounds__(256) void bin_kernel(
    const int* __restrict__ ei, const float* __restrict__ ew,
    int* __restrict__ cursor, unsigned* __restrict__ pk)
{
    const int e = blockIdx.x * 256 + threadIdx.x;
    if (e >= E_EDGES) return;
    const int row = ei[e];
    const int pos = atomicAdd(&cursor[row], 1);
    const unsigned q = (unsigned)(ew[e] * 32767.f + 0.5f);
    pk[pos] = (unsigned)ei[E_EDGES + e] | (q << 17);
}

// ---- Phase 3: energy + exp fused (no global max: |en| <= ~6, overflow-safe;
// softmax shift-invariant). 16 edges/wave in flight. p[] written linearly. ----
__global__ __launch_bounds__(256) void energy_kernel(
    const float* __restrict__ Q, const unsigned short* __restrict__ Kb,
    const int* __restrict__ offs, const int* __restrict__ counts,
    const unsigned* __restrict__ pk, float* __restrict__ p_arr,
    float* __restrict__ blocksum)
{
    const int row  = (blockIdx.x * 256 + threadIdx.x) >> 6;
    const int lane = threadIdx.x & 63;
    const int eg   = lane >> 4;     // edge group 0..3
    const int sl   = lane & 15;     // sub-lane in group
    const int start = offs[row], len = counts[row];
    const float4 q0 = *(const float4*)&Q[(size_t)row * HDIM + sl * 8];
    const float4 q1 = *(const float4*)&Q[(size_t)row * HDIM + sl * 8 + 4];
    const uint4* kb128 = (const uint4*)Kb;   // one row = 16 uint4
    const float inv_scale = 0.08838834764831845f;  // 1/sqrt(128)
    const float dq = 1.0f / 32767.0f;
    float psum = 0.f;
    for (int j0 = 0; j0 < len; j0 += 16) {
        int e[4]; bool v[4]; unsigned r[4]; uint4 u[4];
#pragma unroll
        for (int c = 0; c < 4; ++c) {
            const int jj = j0 + c * 4 + eg;
            v[c] = jj < len;
            e[c] = start + (v[c] ? jj : 0);
            r[c] = pk[e[c]];
        }
#pragma unroll
        for (int c = 0; c < 4; ++c)
            u[c] = kb128[(size_t)(r[c] & 0x1FFFFu) * 16 + sl];
#pragma unroll
        for (int c = 0; c < 4; ++c) {
            float d = q0.x * bflo(u[c].x) + q0.y * bfhi(u[c].x)
                    + q0.z * bflo(u[c].y) + q0.w * bfhi(u[c].y)
                    + q1.x * bflo(u[c].z) + q1.y * bfhi(u[c].z)
                    + q1.z * bflo(u[c].w) + q1.w * bfhi(u[c].w);
#pragma unroll
            for (int m = 8; m >= 1; m >>= 1) d += __shfl_xor(d, m);
            const float ewv = (float)(r[c] >> 17) * dq;
            const float p = __expf(d * inv_scale * ewv);
            if (v[c] && sl == 0) { p_arr[e[c]] = p; psum += p; }
        }
    }
    psum += __shfl_xor(psum, 16);
    psum += __shfl_xor(psum, 32);
    __shared__ float sm[4];
    if (lane == 0) sm[threadIdx.x >> 6] = psum;
    __syncthreads();
    if (threadIdx.x == 0)
        blocksum[blockIdx.x] = sm[0] + sm[1] + sm[2] + sm[3];
}

__global__ __launch_bounds__(256) void reduce_sum_kernel(
    const float* __restrict__ bs, int n, float* __restrict__ gsum)
{
    float v = 0.f;
    for (int i = threadIdx.x; i < n; i += 256) v += bs[i];
#pragma unroll
    for (int s = 32; s >= 1; s >>= 1) v += __shfl_xor(v, s);
    __shared__ float sm[4];
    if ((threadIdx.x & 63) == 0) sm[threadIdx.x >> 6] = v;
    __syncthreads();
    if (threadIdx.x == 0) *gsum = sm[0] + sm[1] + sm[2] + sm[3];
}

// ---- Phase 5: out[row] = sum_j V[col_j] * p_j / gsum; 16 edges in flight ----
__global__ __launch_bounds__(256) void accum_kernel(
    const unsigned short* __restrict__ Vb,
    const int* __restrict__ offs, const int* __restrict__ counts,
    const unsigned* __restrict__ pk, const float* __restrict__ p_arr,
    const float* __restrict__ gsum, float* __restrict__ out)
{
    const int row  = (blockIdx.x * 256 + threadIdx.x) >> 6;
    const int lane = threadIdx.x & 63;
    const int eg   = lane >> 4;     // edge group 0..3
    const int sl   = lane & 15;     // sub-lane: dims sl*8..sl*8+7
    const float inv = 1.0f / *gsum;
    const int start = offs[row], len = counts[row];
    const uint4* vb128 = (const uint4*)Vb;   // one row = 16 uint4
    float acc[4][8];
#pragma unroll
    for (int c = 0; c < 4; ++c)
#pragma unroll
        for (int k = 0; k < 8; ++k) acc[c][k] = 0.f;
    for (int j0 = 0; j0 < len; j0 += 16) {
        unsigned r[4]; float w[4]; uint4 u[4];
#pragma unroll
        for (int c = 0; c < 4; ++c) {
            const int jj = j0 + c * 4 + eg;
            const bool v = jj < len;
            const int  e = start + (v ? jj : 0);
            r[c] = pk[e];
            w[c] = v ? p_arr[e] * inv : 0.f;
        }
#pragma unroll
        for (int c = 0; c < 4; ++c)
            u[c] = vb128[(size_t)(r[c] & 0x1FFFFu) * 16 + sl];
#pragma unroll
        for (int c = 0; c < 4; ++c) {
            acc[c][0] += bflo(u[c].x) * w[c];
            acc[c][1] += bfhi(u[c].x) * w[c];
            acc[c][2] += bflo(u[c].y) * w[c];
            acc[c][3] += bfhi(u[c].y) * w[c];
            acc[c][4] += bflo(u[c].z) * w[c];
            acc[c][5] += bfhi(u[c].z) * w[c];
            acc[c][6] += bflo(u[c].w) * w[c];
            acc[c][7] += bfhi(u[c].w) * w[c];
        }
    }
    float a[8];
#pragma unroll
    for (int k = 0; k < 8; ++k) {
        a[k] = (acc[0][k] + acc[1][k]) + (acc[2][k] + acc[3][k]);
        a[k] += __shfl_xor(a[k], 16);
        a[k] += __shfl_xor(a[k], 32);
    }
    if (eg == 0) {
        float* o = out + (size_t)row * HDIM + sl * 8;
        *(float4*)o       = make_float4(a[0], a[1], a[2], a[3]);
        *(float4*)(o + 4) = make_float4(a[4], a[5], a[6], a[7]);
    }
}

extern "C" void kernel_launch(void* const* d_in, const int* in_sizes, int n_in,
                              void* d_out, int out_size, void* d_ws, size_t ws_size,
                              hipStream_t stream)
{
    const float* x  = (const float*)d_in[0];
    const int*   ei = (const int*)d_in[1];
    const float* ew = (const float*)d_in[2];
    const float* Wq = (const float*)d_in[3];
    const float* bq = (const float*)d_in[4];
    const float* Wk = (const float*)d_in[5];
    const float* bk = (const float*)d_in[6];
    const float* Wv = (const float*)d_in[7];
    const float* bv = (const float*)d_in[8];
    float* out = (float*)d_out;

    float* ws = (float*)d_ws;
    float* Q       = ws;                                  // N*H fp32
    unsigned short* Kb = (unsigned short*)(Q + (size_t)N_NODES * HDIM);  // N*H bf16
    unsigned short* Vb = Kb + (size_t)N_NODES * HDIM;     // N*H bf16
    int*   counts  = (int*)(Vb + (size_t)N_NODES * HDIM); // N
    int*   offs    = counts + N_NODES;                    // N
    int*   cursor  = offs + N_NODES;                      // N
    int*   aux     = cursor + N_NODES;                    // SCAN_BLOCKS (256 slots)
    unsigned* pk   = (unsigned*)(aux + 256);              // E packed (col|ew_q15)
    float* p_arr   = (float*)(pk + E_EDGES);              // E
    float* blocksum= p_arr + E_EDGES;                     // ROW_BLOCKS
    float* gsum    = blocksum + ROW_BLOCKS;               // 1

    hipMemsetAsync(counts, 0, N_NODES * sizeof(int), stream);

    qkv_hist_kernel<<<3 * QKV_BLOCKS, 256, 0, stream>>>(
        x, Wq, bq, Wk, bk, Wv, bv, ei, counts, Q, Kb, Vb);
    scan_partial_kernel<<<SCAN_BLOCKS, 256, 0, stream>>>(counts, offs, aux);
    scan_aux_kernel<<<1, 256, 0, stream>>>(aux);
    scan_add_kernel<<<SCAN_BLOCKS, 256, 0, stream>>>(offs, aux, cursor);
    bin_kernel<<<EDGE_BLOCKS, 256, 0, stream>>>(ei, ew, cursor, pk);
    energy_kernel<<<ROW_BLOCKS, 256, 0, stream>>>(Q, Kb, offs, counts, pk, p_arr, blocksum);
    reduce_sum_kernel<<<1, 256, 0, stream>>>(blocksum, ROW_BLOCKS, gsum);
    accum_kernel<<<ROW_BLOCKS, 256, 0, stream>>>(Vb, offs, counts, pk, p_arr, gsum, out);
}